// Round 1
// baseline (615.484 us; speedup 1.0000x reference)
//
#include <hip/hip_runtime.h>

// QWK loss, MI355X. 302 MB input read -> memory-bound, floor ~46 us @6.6 TB/s.
// Measured breakdown of the 386 us: ~322 us is the harness's 1 GiB workspace
// poison-fill (2 x 160 us fillBufferAligned, not controllable), ~64 us is ours.
// This version:
//  - single fused kernel: 4 positions/thread/iter (8x dwordx4 + int4 in flight)
//    for streaming BW, per-wave LDS histograms, unconditional accumulate
//    (row t==0 dropped at finalize),
//  - last-block-done reduction via device-scope atomics (stage-2 kernel gone);
//    260 B of d_ws zeroed by hipMemsetAsync each launch (graph-capturable).

#define NCATS 8
#define NBINS 64
#define NBLK  2048          // 2048 blocks * 4 waves = 32 waves/CU

__global__ __launch_bounds__(256) void qwk_fused_kernel(
    const float* __restrict__ logits,
    const int* __restrict__ targets,
    unsigned int* __restrict__ ghist,   // [NBINS], pre-zeroed
    unsigned int* __restrict__ cnt,     // ticket counter, pre-zeroed
    float* __restrict__ out,
    int npos)
{
    __shared__ unsigned int lh[4][NBINS];   // per-wave private histograms
    const int tid = threadIdx.x;
    ((unsigned int*)lh)[tid] = 0u;          // 256 threads zero 256 entries
    __syncthreads();

    unsigned int* wh = lh[tid >> 6];

    auto amax = [](const float4& a, const float4& b) -> int {
        int best = 0; float bv = a.x;               // strict > keeps first
        if (a.y > bv) { bv = a.y; best = 1; }       // occurrence, == jnp.argmax
        if (a.z > bv) { bv = a.z; best = 2; }
        if (a.w > bv) { bv = a.w; best = 3; }
        if (b.x > bv) { bv = b.x; best = 4; }
        if (b.y > bv) { bv = b.y; best = 5; }
        if (b.z > bv) { bv = b.z; best = 6; }
        if (b.w > bv) { bv = b.w; best = 7; }
        return best;
    };

    const int stride4 = gridDim.x * blockDim.x * 4;
    int pos = (blockIdx.x * blockDim.x + tid) * 4;

    for (; pos + 3 < npos; pos += stride4) {
        const float4* lp = (const float4*)(logits + (size_t)pos * NCATS);
        float4 a0 = lp[0], b0 = lp[1];
        float4 a1 = lp[2], b1 = lp[3];
        float4 a2 = lp[4], b2 = lp[5];
        float4 a3 = lp[6], b3 = lp[7];
        int4 t4 = *(const int4*)(targets + pos);

        atomicAdd(&wh[(t4.x << 3) | amax(a0, b0)], 1u);
        atomicAdd(&wh[(t4.y << 3) | amax(a1, b1)], 1u);
        atomicAdd(&wh[(t4.z << 3) | amax(a2, b2)], 1u);
        atomicAdd(&wh[(t4.w << 3) | amax(a3, b3)], 1u);
    }
    // tail (never taken for B*S = 8.4M, kept for generality)
    if (pos < npos) {
        int end = min(pos + 4, npos);
        for (; pos < end; ++pos) {
            const float4* lp = (const float4*)(logits + (size_t)pos * NCATS);
            float4 a = lp[0], b = lp[1];
            atomicAdd(&wh[(targets[pos] << 3) | amax(a, b)], 1u);
        }
    }
    __syncthreads();

    // block-level reduce -> device-scope global histogram
    if (tid < NBINS) {
        unsigned int s = lh[0][tid] + lh[1][tid] + lh[2][tid] + lh[3][tid];
        atomicAdd(&ghist[tid], s);
    }
    __threadfence();          // release: hist RMWs visible before ticket
    __syncthreads();

    __shared__ unsigned int lastFlag;
    if (tid == 0)
        lastFlag = (atomicAdd(cnt, 1u) == (unsigned)gridDim.x - 1u) ? 1u : 0u;
    __syncthreads();
    if (!lastFlag) return;

    // ---- last block: finalize (double precision; counts < 2^24 exact) ----
    __shared__ double cm[NBINS];
    if (tid < NBINS)          // row 0 (t==0) is masked out of the reference cm
        cm[tid] = (tid < NCATS) ? 0.0
                                : (double)atomicAdd(&ghist[tid], 0u); // coherent read
    __syncthreads();

    if (tid == 0) {
        double n = 0.0;
        #pragma unroll
        for (int i = 0; i < NBINS; ++i) n += cm[i];

        double loss;
        if (n == 0.0) {
            loss = 0.0;  // n==0 -> qwk=1 -> loss 0
        } else {
            double inv = 1.0 / n;
            double mt[NCATS], mp[NCATS];
            #pragma unroll
            for (int i = 0; i < NCATS; ++i) { mt[i] = 0.0; mp[i] = 0.0; }
            #pragma unroll
            for (int i = 0; i < NCATS; ++i) {
                #pragma unroll
                for (int j = 0; j < NCATS; ++j) {
                    double c = cm[i * NCATS + j] * inv;
                    mt[i] += c;
                    mp[j] += c;
                }
            }
            double num = 0.0, den = 0.0;
            #pragma unroll
            for (int i = 0; i < NCATS; ++i) {
                #pragma unroll
                for (int j = 0; j < NCATS; ++j) {
                    double d = (double)(i - j);
                    double w = 1.0 - d * d / 49.0;   // (NCATS-1)^2 = 49
                    num += w * (cm[i * NCATS + j] * inv);
                    den += w * (mt[i] * mp[j]);
                }
            }
            double qwk = (den == 0.0) ? 0.0 : (num / den);
            loss = 1.0 - qwk;
        }
        out[0] = (float)loss;
    }
}

extern "C" void kernel_launch(void* const* d_in, const int* in_sizes, int n_in,
                              void* d_out, int out_size, void* d_ws, size_t ws_size,
                              hipStream_t stream)
{
    const float* logits = (const float*)d_in[0];
    const int* targets = (const int*)d_in[1];
    float* out = (float*)d_out;
    unsigned int* ghist = (unsigned int*)d_ws;      // [NBINS] totals
    unsigned int* cnt   = ghist + NBINS;            // ticket counter

    const int npos = in_sizes[0] / NCATS;           // = BATCH*SEQ

    hipMemsetAsync(d_ws, 0, (NBINS + 1) * sizeof(unsigned int), stream);
    qwk_fused_kernel<<<NBLK, 256, 0, stream>>>(logits, targets, ghist, cnt, out, npos);
}

// Round 3
// 388.122 us; speedup vs baseline: 1.5858x; 1.5858x over previous
//
#include <hip/hip_runtime.h>

// QWK loss, MI355X. 302 MB input read -> memory-bound, floor ~46 us @6.3 TB/s.
// Wall-time breakdown (measured r0): ~322 us = harness 1 GiB workspace poison
// (2 x 160 us fillBufferAligned, not controllable); addressable part is
// stage1 (~58 us) + stage2 (~6 us).
// r1 post-mortem: fusing stage2 via device-scope atomicAdd on a 64-bin global
// histogram serialized 131K cross-XCD same-line RMWs -> 357 us (424 GB/s,
// VALU 1.5%). NEVER funnel per-block results through contended far-atomics.
// r2: two-kernel structure restored; stage1 gets 4 pos/thread (12 loads in
// flight), per-wave LDS histograms, branchless accumulate (row 0 dropped at
// finalize). Partials are plain per-block stores (overwritten, no zeroing).
// (r2 bench was an infra failure — container acquisition; kernel unmeasured,
// resubmitted unchanged in r3.)

#define NCATS 8
#define NBINS 64
#define NPART 2048          // stage-1 blocks; 2048 blocks * 4 waves = 32 waves/CU

__global__ __launch_bounds__(256) void qwk_hist_kernel(
    const float* __restrict__ logits,
    const int* __restrict__ targets,
    unsigned int* __restrict__ part,   // [NPART][NBINS]
    int npos)
{
    __shared__ unsigned int lh[4][NBINS];   // per-wave private histograms
    const int tid = threadIdx.x;
    ((unsigned int*)lh)[tid] = 0u;          // 256 threads zero 4*64 entries
    __syncthreads();

    unsigned int* wh = lh[tid >> 6];

    auto amax = [](const float4& a, const float4& b) -> int {
        int best = 0; float bv = a.x;               // strict > keeps first
        if (a.y > bv) { bv = a.y; best = 1; }       // occurrence == jnp.argmax
        if (a.z > bv) { bv = a.z; best = 2; }
        if (a.w > bv) { bv = a.w; best = 3; }
        if (b.x > bv) { bv = b.x; best = 4; }
        if (b.y > bv) { bv = b.y; best = 5; }
        if (b.z > bv) { bv = b.z; best = 6; }
        if (b.w > bv) { bv = b.w; best = 7; }
        return best;
    };

    // Each block covers a contiguous 1024-position window per outer iter:
    // slot j = base + j*256, lane-stride 32 B on logits (proven-coalesced).
    const int stride = gridDim.x * blockDim.x * 4;
    int base = blockIdx.x * (blockDim.x * 4) + tid;

    for (; base + 3 * 256 < npos; base += stride) {
        const float4* lp = (const float4*)logits;
        float4 a0 = lp[(size_t)(base        ) * 2    ];
        float4 b0 = lp[(size_t)(base        ) * 2 + 1];
        float4 a1 = lp[(size_t)(base +  256 ) * 2    ];
        float4 b1 = lp[(size_t)(base +  256 ) * 2 + 1];
        float4 a2 = lp[(size_t)(base +  512 ) * 2    ];
        float4 b2 = lp[(size_t)(base +  512 ) * 2 + 1];
        float4 a3 = lp[(size_t)(base +  768 ) * 2    ];
        float4 b3 = lp[(size_t)(base +  768 ) * 2 + 1];
        int t0 = targets[base];
        int t1 = targets[base + 256];
        int t2 = targets[base + 512];
        int t3 = targets[base + 768];

        atomicAdd(&wh[(t0 << 3) | amax(a0, b0)], 1u);   // branchless: row 0
        atomicAdd(&wh[(t1 << 3) | amax(a1, b1)], 1u);   // (t==0) discarded in
        atomicAdd(&wh[(t2 << 3) | amax(a2, b2)], 1u);   // the finalize kernel
        atomicAdd(&wh[(t3 << 3) | amax(a3, b3)], 1u);
    }
    // tail (not taken for B*S = 8.4M = 4*stride exactly; kept for generality)
    for (; base < npos; base += 256) {
        const float4* lp = (const float4*)(logits + (size_t)base * NCATS);
        float4 a = lp[0], b = lp[1];
        atomicAdd(&wh[(targets[base] << 3) | amax(a, b)], 1u);
    }
    __syncthreads();

    if (tid < NBINS)
        part[blockIdx.x * NBINS + tid] =
            lh[0][tid] + lh[1][tid] + lh[2][tid] + lh[3][tid];
}

__global__ __launch_bounds__(256) void qwk_final_kernel(
    const unsigned int* __restrict__ part,
    float* __restrict__ out)
{
    __shared__ unsigned int sums[256];
    __shared__ double cm[NBINS];
    const int t = threadIdx.x;
    const int bin = t & 63;
    const int stripe = t >> 6;                 // 4 stripes of NPART/4 blocks
    const int per = NPART / 4;

    unsigned int s = 0;
    #pragma unroll 8
    for (int i = 0; i < per; ++i)
        s += part[(size_t)(stripe * per + i) * NBINS + bin];
    sums[t] = s;
    __syncthreads();

    if (t < NBINS)     // rows with target==0 are masked out of the reference cm
        cm[t] = (t < NCATS) ? 0.0
              : (double)(sums[t] + sums[t + 64] + sums[t + 128] + sums[t + 192]);
    __syncthreads();

    if (t == 0) {
        double n = 0.0;
        #pragma unroll
        for (int i = 0; i < NBINS; ++i) n += cm[i];

        double loss;
        if (n == 0.0) {
            loss = 0.0;  // n==0 -> qwk=1 -> loss 0
        } else {
            double inv = 1.0 / n;
            double mt[NCATS], mp[NCATS];
            #pragma unroll
            for (int i = 0; i < NCATS; ++i) { mt[i] = 0.0; mp[i] = 0.0; }
            #pragma unroll
            for (int i = 0; i < NCATS; ++i) {
                #pragma unroll
                for (int j = 0; j < NCATS; ++j) {
                    double c = cm[i * NCATS + j] * inv;
                    mt[i] += c;
                    mp[j] += c;
                }
            }
            double num = 0.0, den = 0.0;
            #pragma unroll
            for (int i = 0; i < NCATS; ++i) {
                #pragma unroll
                for (int j = 0; j < NCATS; ++j) {
                    double d = (double)(i - j);
                    double w = 1.0 - d * d / 49.0;   // (NCATS-1)^2 = 49
                    num += w * (cm[i * NCATS + j] * inv);
                    den += w * (mt[i] * mp[j]);
                }
            }
            double qwk = (den == 0.0) ? 0.0 : (num / den);
            loss = 1.0 - qwk;
        }
        out[0] = (float)loss;
    }
}

extern "C" void kernel_launch(void* const* d_in, const int* in_sizes, int n_in,
                              void* d_out, int out_size, void* d_ws, size_t ws_size,
                              hipStream_t stream)
{
    const float* logits = (const float*)d_in[0];
    const int* targets = (const int*)d_in[1];
    float* out = (float*)d_out;
    unsigned int* part = (unsigned int*)d_ws;   // NPART*NBINS uints, overwritten

    const int npos = in_sizes[0] / NCATS;       // = BATCH*SEQ

    qwk_hist_kernel<<<NPART, 256, 0, stream>>>(logits, targets, part, npos);
    qwk_final_kernel<<<1, 256, 0, stream>>>(part, out);
}

// Round 5
// 362.554 us; speedup vs baseline: 1.6976x; 1.0705x over previous
//
#include <hip/hip_runtime.h>

// QWK loss, MI355X. 302 MB input read -> memory-bound, floor ~46 us @6.6 TB/s.
// Wall-time breakdown (measured r0/r3): ~322 us = harness 1 GiB workspace
// poison (2 x 160 us fillBufferAligned, not controllable); addressable part
// is stage1 (~58 us @ ~5.3 TB/s) + stage2 (~6 us).
// r1: device-scope atomic histogram = 357 us disaster (cross-XCD same-line
//     RMW serialization). Reverted permanently.
// r3: 4 pos/thread + per-wave LDS hists + branchless = exactly baseline ->
//     stage1 not limited by MLP, LDS atomics, or divergence.
// r4: dense-stride rewrite failed to COMPILE (__builtin_nontemporal_load
//     rejects HIP_vector_type float4*). r5 = same kernel with a clang native
//     ext_vector_type(4) for the NT loads. Theory still: the 32B-per-lane
//     strided logits access (2 KB footprint / 32 lines per wave-inst, each
//     line touched twice) is the gap to fill-kernel BW. Dense version: lane l
//     loads float4 2Pw+j*64+l (stride 16 B); lane pair combines halves via
//     one shfl_xor + tie-correct select (lo half wins ties == first-occurrence
//     argmax); even lane does the LDS atomic.

#define NCATS 8
#define NBINS 64
#define NPART 2048          // stage-1 blocks; 2048 blocks * 4 waves = 32 waves/CU

typedef float f4 __attribute__((ext_vector_type(4)));   // NT-load-compatible

__global__ __launch_bounds__(256) void qwk_hist_kernel(
    const float* __restrict__ logits,
    const int* __restrict__ targets,
    unsigned int* __restrict__ part,   // [NPART][NBINS]
    int npos)
{
    __shared__ unsigned int lh[4][NBINS];   // per-wave private histograms
    const int tid = threadIdx.x;
    ((unsigned int*)lh)[tid] = 0u;          // 256 threads zero 4*64 entries
    __syncthreads();

    unsigned int* wh = lh[tid >> 6];
    const int wv    = tid >> 6;
    const int lane  = tid & 63;
    const int half  = lane & 1;     // 0: holds logits[0..3], 1: logits[4..7]
    const int pairk = lane >> 1;    // 0..31: position within 32-pos batch

    const f4* lp = (const f4*)logits;

    // Each wave owns a contiguous 256-position window per grid iteration.
    const int stride = gridDim.x * 1024;          // block covers 1024 positions
    int Pw = blockIdx.x * 1024 + wv * 256;

    for (; Pw + 256 <= npos; Pw += stride) {
        f4  f[8];
        int tg[8];
        #pragma unroll
        for (int j = 0; j < 8; ++j)   // fully dense: lane-stride 16 B
            f[j] = __builtin_nontemporal_load(&lp[(size_t)Pw * 2 + j * 64 + lane]);
        #pragma unroll
        for (int j = 0; j < 8; ++j)   // both lanes of a pair load same addr
            tg[j] = __builtin_nontemporal_load(&targets[Pw + j * 32 + pairk]);

        #pragma unroll
        for (int j = 0; j < 8; ++j) {
            f4 a = f[j];
            int bi = half << 2; float bv = a.x;       // strict > keeps first
            if (a.y > bv) { bv = a.y; bi = (half << 2) | 1; }
            if (a.z > bv) { bv = a.z; bi = (half << 2) | 2; }
            if (a.w > bv) { bv = a.w; bi = (half << 2) | 3; }
            float obv = __shfl_xor(bv, 1);
            int   obi = __shfl_xor(bi, 1);
            // lo = indices 0-3 half, hi = indices 4-7 half; hi wins only if >
            float lov = half ? obv : bv;  int loi = half ? obi : bi;
            float hiv = half ? bv : obv;  int hii = half ? bi : obi;
            int best = (hiv > lov) ? hii : loi;
            if (!half) atomicAdd(&wh[(tg[j] << 3) | best], 1u);
        }
    }

    // Generic tail (never taken for B*S = 8.4M = 4*stride exactly).
    for (; Pw < npos; Pw += stride) {
        #pragma unroll
        for (int j = 0; j < 8; ++j) {
            int p = Pw + j * 32 + pairk;              // pair-uniform guard:
            if (p < npos) {                           // shfl partner active
                f4 a = lp[(size_t)p * 2 + half];
                int t = targets[p];
                int bi = half << 2; float bv = a.x;
                if (a.y > bv) { bv = a.y; bi = (half << 2) | 1; }
                if (a.z > bv) { bv = a.z; bi = (half << 2) | 2; }
                if (a.w > bv) { bv = a.w; bi = (half << 2) | 3; }
                float obv = __shfl_xor(bv, 1);
                int   obi = __shfl_xor(bi, 1);
                float lov = half ? obv : bv;  int loi = half ? obi : bi;
                float hiv = half ? bv : obv;  int hii = half ? bi : obi;
                int best = (hiv > lov) ? hii : loi;
                if (!half) atomicAdd(&wh[(t << 3) | best], 1u);
            }
        }
    }
    __syncthreads();

    if (tid < NBINS)
        part[blockIdx.x * NBINS + tid] =
            lh[0][tid] + lh[1][tid] + lh[2][tid] + lh[3][tid];
}

__global__ __launch_bounds__(256) void qwk_final_kernel(
    const unsigned int* __restrict__ part,
    float* __restrict__ out)
{
    __shared__ unsigned int sums[256];
    __shared__ double cm[NBINS];
    const int t = threadIdx.x;
    const int bin = t & 63;
    const int stripe = t >> 6;                 // 4 stripes of NPART/4 blocks
    const int per = NPART / 4;

    unsigned int s = 0;
    #pragma unroll 8
    for (int i = 0; i < per; ++i)
        s += part[(size_t)(stripe * per + i) * NBINS + bin];
    sums[t] = s;
    __syncthreads();

    if (t < NBINS)     // rows with target==0 are masked out of the reference cm
        cm[t] = (t < NCATS) ? 0.0
              : (double)(sums[t] + sums[t + 64] + sums[t + 128] + sums[t + 192]);
    __syncthreads();

    if (t == 0) {
        double n = 0.0;
        #pragma unroll
        for (int i = 0; i < NBINS; ++i) n += cm[i];

        double loss;
        if (n == 0.0) {
            loss = 0.0;  // n==0 -> qwk=1 -> loss 0
        } else {
            double inv = 1.0 / n;
            double mt[NCATS], mp[NCATS];
            #pragma unroll
            for (int i = 0; i < NCATS; ++i) { mt[i] = 0.0; mp[i] = 0.0; }
            #pragma unroll
            for (int i = 0; i < NCATS; ++i) {
                #pragma unroll
                for (int j = 0; j < NCATS; ++j) {
                    double c = cm[i * NCATS + j] * inv;
                    mt[i] += c;
                    mp[j] += c;
                }
            }
            double num = 0.0, den = 0.0;
            #pragma unroll
            for (int i = 0; i < NCATS; ++i) {
                #pragma unroll
                for (int j = 0; j < NCATS; ++j) {
                    double d = (double)(i - j);
                    double w = 1.0 - d * d / 49.0;   // (NCATS-1)^2 = 49
                    num += w * (cm[i * NCATS + j] * inv);
                    den += w * (mt[i] * mp[j]);
                }
            }
            double qwk = (den == 0.0) ? 0.0 : (num / den);
            loss = 1.0 - qwk;
        }
        out[0] = (float)loss;
    }
}

extern "C" void kernel_launch(void* const* d_in, const int* in_sizes, int n_in,
                              void* d_out, int out_size, void* d_ws, size_t ws_size,
                              hipStream_t stream)
{
    const float* logits = (const float*)d_in[0];
    const int* targets = (const int*)d_in[1];
    float* out = (float*)d_out;
    unsigned int* part = (unsigned int*)d_ws;   // NPART*NBINS uints, overwritten

    const int npos = in_sizes[0] / NCATS;       // = BATCH*SEQ

    qwk_hist_kernel<<<NPART, 256, 0, stream>>>(logits, targets, part, npos);
    qwk_final_kernel<<<1, 256, 0, stream>>>(part, out);
}

// Round 6
// 357.042 us; speedup vs baseline: 1.7238x; 1.0154x over previous
//
#include <hip/hip_runtime.h>

// QWK loss, MI355X. 302 MB input read -> memory-bound.
// Wall breakdown (r5, 362.6 us): ~323 us = harness 1 GiB workspace poison
// (2 x 161 us fillBufferAligned, not controllable); stage1 ~34 us (dense
// 16B/lane NT stream, ~8.9 TB/s effective -> L3-assisted, above HBM peak);
// stage2 ~6 us.
// r1: device-scope atomic histogram = 357 us disaster (cross-XCD same-line
//     RMW serialization). Reverted permanently.
// r3: more MLP/LDS-privatization/branchless = null -> not the limiter.
// r5: dense-stride + shfl-pair argmax + NT loads: 388 -> 362.6 us (-25.5).
// r6: only remaining addressable slack is stage2: partials packed to u16
//     (per-block counts <= 4096), 256 KB instead of 512 KB, and a 1024-thread
//     final kernel (16 stripes x 128 blocks). Stage1 untouched except the
//     narrower coalesced partial store.

#define NCATS 8
#define NBINS 64
#define NPART 2048          // stage-1 blocks; 2048 blocks * 4 waves = 32 waves/CU

typedef float f4 __attribute__((ext_vector_type(4)));   // NT-load-compatible

__global__ __launch_bounds__(256) void qwk_hist_kernel(
    const float* __restrict__ logits,
    const int* __restrict__ targets,
    unsigned short* __restrict__ part,   // [NPART][NBINS], counts <= 4096
    int npos)
{
    __shared__ unsigned int lh[4][NBINS];   // per-wave private histograms
    const int tid = threadIdx.x;
    ((unsigned int*)lh)[tid] = 0u;          // 256 threads zero 4*64 entries
    __syncthreads();

    unsigned int* wh = lh[tid >> 6];
    const int wv    = tid >> 6;
    const int lane  = tid & 63;
    const int half  = lane & 1;     // 0: holds logits[0..3], 1: logits[4..7]
    const int pairk = lane >> 1;    // 0..31: position within 32-pos batch

    const f4* lp = (const f4*)logits;

    // Each wave owns a contiguous 256-position window per grid iteration.
    const int stride = gridDim.x * 1024;          // block covers 1024 positions
    int Pw = blockIdx.x * 1024 + wv * 256;

    for (; Pw + 256 <= npos; Pw += stride) {
        f4  f[8];
        int tg[8];
        #pragma unroll
        for (int j = 0; j < 8; ++j)   // fully dense: lane-stride 16 B
            f[j] = __builtin_nontemporal_load(&lp[(size_t)Pw * 2 + j * 64 + lane]);
        #pragma unroll
        for (int j = 0; j < 8; ++j)   // both lanes of a pair load same addr
            tg[j] = __builtin_nontemporal_load(&targets[Pw + j * 32 + pairk]);

        #pragma unroll
        for (int j = 0; j < 8; ++j) {
            f4 a = f[j];
            int bi = half << 2; float bv = a.x;       // strict > keeps first
            if (a.y > bv) { bv = a.y; bi = (half << 2) | 1; }
            if (a.z > bv) { bv = a.z; bi = (half << 2) | 2; }
            if (a.w > bv) { bv = a.w; bi = (half << 2) | 3; }
            float obv = __shfl_xor(bv, 1);
            int   obi = __shfl_xor(bi, 1);
            // lo = indices 0-3 half, hi = indices 4-7 half; hi wins only if >
            float lov = half ? obv : bv;  int loi = half ? obi : bi;
            float hiv = half ? bv : obv;  int hii = half ? bi : obi;
            int best = (hiv > lov) ? hii : loi;
            if (!half) atomicAdd(&wh[(tg[j] << 3) | best], 1u);
        }
    }

    // Generic tail (never taken for B*S = 8.4M = 4*stride exactly).
    for (; Pw < npos; Pw += stride) {
        #pragma unroll
        for (int j = 0; j < 8; ++j) {
            int p = Pw + j * 32 + pairk;              // pair-uniform guard:
            if (p < npos) {                           // shfl partner active
                f4 a = lp[(size_t)p * 2 + half];
                int t = targets[p];
                int bi = half << 2; float bv = a.x;
                if (a.y > bv) { bv = a.y; bi = (half << 2) | 1; }
                if (a.z > bv) { bv = a.z; bi = (half << 2) | 2; }
                if (a.w > bv) { bv = a.w; bi = (half << 2) | 3; }
                float obv = __shfl_xor(bv, 1);
                int   obi = __shfl_xor(bi, 1);
                float lov = half ? obv : bv;  int loi = half ? obi : bi;
                float hiv = half ? bv : obv;  int hii = half ? bi : obi;
                int best = (hiv > lov) ? hii : loi;
                if (!half) atomicAdd(&wh[(t << 3) | best], 1u);
            }
        }
    }
    __syncthreads();

    if (tid < NBINS)    // per-block count <= npos/NPART = 4096, fits u16
        part[blockIdx.x * NBINS + tid] = (unsigned short)
            (lh[0][tid] + lh[1][tid] + lh[2][tid] + lh[3][tid]);
}

__global__ __launch_bounds__(1024) void qwk_final_kernel(
    const unsigned short* __restrict__ part,
    float* __restrict__ out)
{
    __shared__ unsigned int sums[1024];
    __shared__ double cm[NBINS];
    const int t = threadIdx.x;
    const int bin = t & 63;
    const int stripe = t >> 6;                 // 16 stripes of NPART/16 blocks
    const int per = NPART / 16;                // 128

    unsigned int s = 0;
    #pragma unroll 8
    for (int i = 0; i < per; ++i)
        s += part[(size_t)(stripe * per + i) * NBINS + bin];
    sums[t] = s;
    __syncthreads();

    if (t < NBINS) {   // rows with target==0 are masked out of the reference cm
        unsigned int tot = 0;
        #pragma unroll
        for (int st = 0; st < 16; ++st) tot += sums[st * 64 + t];
        cm[t] = (t < NCATS) ? 0.0 : (double)tot;
    }
    __syncthreads();

    if (t == 0) {
        double n = 0.0;
        #pragma unroll
        for (int i = 0; i < NBINS; ++i) n += cm[i];

        double loss;
        if (n == 0.0) {
            loss = 0.0;  // n==0 -> qwk=1 -> loss 0
        } else {
            double inv = 1.0 / n;
            double mt[NCATS], mp[NCATS];
            #pragma unroll
            for (int i = 0; i < NCATS; ++i) { mt[i] = 0.0; mp[i] = 0.0; }
            #pragma unroll
            for (int i = 0; i < NCATS; ++i) {
                #pragma unroll
                for (int j = 0; j < NCATS; ++j) {
                    double c = cm[i * NCATS + j] * inv;
                    mt[i] += c;
                    mp[j] += c;
                }
            }
            double num = 0.0, den = 0.0;
            #pragma unroll
            for (int i = 0; i < NCATS; ++i) {
                #pragma unroll
                for (int j = 0; j < NCATS; ++j) {
                    double d = (double)(i - j);
                    double w = 1.0 - d * d / 49.0;   // (NCATS-1)^2 = 49
                    num += w * (cm[i * NCATS + j] * inv);
                    den += w * (mt[i] * mp[j]);
                }
            }
            double qwk = (den == 0.0) ? 0.0 : (num / den);
            loss = 1.0 - qwk;
        }
        out[0] = (float)loss;
    }
}

extern "C" void kernel_launch(void* const* d_in, const int* in_sizes, int n_in,
                              void* d_out, int out_size, void* d_ws, size_t ws_size,
                              hipStream_t stream)
{
    const float* logits = (const float*)d_in[0];
    const int* targets = (const int*)d_in[1];
    float* out = (float*)d_out;
    unsigned short* part = (unsigned short*)d_ws;  // NPART*NBINS u16, overwritten

    const int npos = in_sizes[0] / NCATS;          // = BATCH*SEQ

    qwk_hist_kernel<<<NPART, 256, 0, stream>>>(logits, targets, part, npos);
    qwk_final_kernel<<<1, 1024, 0, stream>>>(part, out);
}